// Round 15
// baseline (1087.515 us; speedup 1.0000x reference)
//
#include <hip/hip_runtime.h>
#include <math.h>

// MetaNETS Langevin sampler, MI355X — round 20: R19 + phase-A remap ONLY.
// R19: 829.5us (best). R17's bundle contained an untested component: the
// intra-wave phase-A remap. This round isolates it (scalar fma, NO pk):
// wave w lanes 0-31 -> zw1[32w..+32), lanes 32-63 -> f1[32w..+32); dec-L1
// (kc=w) then reads only own-wave zw1 -> B0 syncthreads -> wave_sync.
// Cross-wave zw1 (bwd) / f1sh (S3) reads covered by B1/B3. 4 syncthreads +
// 4 wave_sync per step (was 5+3).
// Everything else identical to R19 (bd1/bf2/bf3 LDS-staged, cvt_pk, ysh/mksh,
// Wd1T-coalesced gz, balanced S3/S4, pair-processed MFMA, (256,4), rW1 hoist,
// tau/h1f aliasing, zold-register race fix, redundant z-update).

#define B_TOT 2048
#define NPT   64
#define ZD    64
#define HD    128

typedef short bh8 __attribute__((ext_vector_type(8)));   // 8 x bf16 (4 VGPR)
typedef float fx4 __attribute__((ext_vector_type(4)));   // MFMA C/D

__device__ __forceinline__ float sigf(float x) {
  return __builtin_amdgcn_rcpf(1.0f + __expf(-x));
}
__device__ __forceinline__ unsigned int bfb(float x) {   // fp32 -> bf16 bits (RNE)
  unsigned int u = __float_as_uint(x);
  u += 0x7FFFu + ((u >> 16) & 1u);
  return u >> 16;
}
__device__ __forceinline__ unsigned int cvtpk(float a, float b) {
  unsigned int r;
  asm("v_cvt_pk_bf16_f32 %0, %1, %2" : "=v"(r) : "v"(a), "v"(b));
  return r;
}
__device__ __forceinline__ float wsum64(float v) {
  #pragma unroll
  for (int d = 1; d < 64; d <<= 1) v += __shfl_xor(v, d, 64);
  return v;
}
__device__ __forceinline__ void wave_sync() {   // intra-wave LDS order + drain
  __builtin_amdgcn_wave_barrier();
  __builtin_amdgcn_s_waitcnt(0xC07F);           // lgkmcnt(0)
  __builtin_amdgcn_wave_barrier();
}

// ws layout: [0,128KB): 4 bf16 B-frag arrays (Wd2, Wd2^T, We2, We3);
//            [128KB,160KB): Wd1T fp32 (Wd1T[h][j] = Wd1[j][h], 128x64).
// B-frag: frag[((kc*8+nt)*64 + L)*8 + j] = W[kc*32 + (L>>4)*8 + j][nt*16 + (L&15)]
__global__ __launch_bounds__(256)
void prep_kernel(const float* __restrict__ Wd2, const float* __restrict__ We2,
                 const float* __restrict__ We3, const float* __restrict__ Wd1,
                 ushort* __restrict__ ws) {
  const int id = blockIdx.x * 256 + threadIdx.x;   // 73728 total
  if (id < 65536) {
    const int arr = id >> 14;
    const int e = id & 16383;
    const int j = e & 7, L = (e >> 3) & 63, nt = (e >> 9) & 7, kc = e >> 12;
    const int kk = kc * 32 + (L >> 4) * 8 + j, nn = nt * 16 + (L & 15);
    float v;
    if      (arr == 0) v = Wd2[kk * HD + nn];
    else if (arr == 1) v = Wd2[nn * HD + kk];    // Wd2^T
    else if (arr == 2) v = We2[kk * HD + nn];
    else               v = We3[kk * HD + nn];
    ws[id] = (ushort)bfb(v);
  } else {
    const int e = id - 65536;                    // [0, 8192)
    const int h = e >> 6, jj = e & 63;
    ((float*)(ws + 65536))[e] = Wd1[jj * HD + h];
  }
}

__global__ __launch_bounds__(256, 4)
void metanets_kernel(
    const float* __restrict__ x_ctx, const float* __restrict__ y_ctx,
    const float* __restrict__ mask,  const float* __restrict__ z0,
    const float* __restrict__ noises,
    const float* __restrict__ We1, const float* __restrict__ be1,
    const float* __restrict__ be2, const float* __restrict__ be3,
    const float* __restrict__ Wd1, const float* __restrict__ bd1,
    const float* __restrict__ bd2, const float* __restrict__ Wd3,
    const float* __restrict__ bd3,
    const float* __restrict__ Wf1, const float* __restrict__ bf1,
    const float* __restrict__ Wf2, const float* __restrict__ bf2,
    const float* __restrict__ Wf3, const float* __restrict__ bf3,
    const ushort* __restrict__ wsfrag,
    float* __restrict__ out, int steps, float dt, float dco)
{
  // h1f doubles as the tau buffer (R7 invariant): within fwd/bwd every wave
  // touches only slots == w (mod 4) and A-frags are reg-loaded before the tau
  // scatter overwrites them.
  __shared__ unsigned int h1f[4096];    // A-frag units: [(slot)*64 + lane] x 4 dw
  __shared__ float zsh[64];
  __shared__ float zw1[128];            // dec-L1 pre-act; f2-partial scratch in S3
  __shared__ float rsh[128];            // encoder r; f2-partial scratch in-loop
  __shared__ float dsumP[512];
  __shared__ float dsumC[128];
  __shared__ float f1sh[128];           // be2 staging, then drift hidden1
  __shared__ float f2sh[128];           // be3 staging, then drift hidden2
  __shared__ float bgz[128];            // f3 k-split partials (2x64)
  __shared__ float rw1sh[128];          // bf1 + r @ Wf1_r (step-invariant)
  __shared__ float wt1sh[128];          // Wf1 t-row staged
  __shared__ float ysh[64], mksh[64];   // y/mask per point (reg relief)
  __shared__ float bd1sh[128];          // bd1 staged (phase-A chain)
  __shared__ float bf2sh[128];          // bf2 staged (S3 chain)
  __shared__ float bf3sh[64];           // bf3 staged (S4 chain)
  __shared__ float bd2sh[128], wd3sh[128], wx0sh[128], wx1sh[128];

  const int tid = threadIdx.x;
  const int lane = tid & 63;                                  // context point
  const int w = __builtin_amdgcn_readfirstlane(tid >> 6);     // wave = m-tile
  const int b = blockIdx.x;
  const int rr = lane & 15, qq = lane >> 4;

  const bh8* Wd2f  = (const bh8*)(wsfrag);
  const bh8* Wd2Tf = (const bh8*)(wsfrag + 16384);
  const bh8* We2f  = (const bh8*)(wsfrag + 32768);
  const bh8* We3f  = (const bh8*)(wsfrag + 49152);
  const float* Wd1T = (const float*)(wsfrag + 65536);   // [128][64] fp32

  const float x0v = x_ctx[(b*NPT + lane)*2 + 0];
  const float x1v = x_ctx[(b*NPT + lane)*2 + 1];
  const float yv  = y_ctx[b*NPT + lane];
  const float mkv = mask[b*NPT + lane];
  const float inv_msum = 1.0f / fmaxf(wsum64(mkv), 1e-6f);
  const float bd3v = bd3[0];

  float x0q[4], x1q[4];
  #pragma unroll
  for (int g = 0; g < 4; ++g) {
    const int src = (w << 4) | (qq << 2) | g;
    x0q[g] = __shfl(x0v, src, 64);
    x1q[g] = __shfl(x1v, src, 64);
  }

  if (tid < 64) {
    zsh[tid]  = z0[b*ZD + tid];
    ysh[tid]  = yv;
    mksh[tid] = mkv;
    bf3sh[tid] = bf3[tid];
  }
  if (tid < 128) {
    bd2sh[tid] = bd2[tid];
    wd3sh[tid] = Wd3[tid];
    wx0sh[tid] = Wd1[64*HD + tid];
    wx1sh[tid] = Wd1[65*HD + tid];
    f1sh[tid]  = be2[tid];
    f2sh[tid]  = be3[tid];
    wt1sh[tid] = Wf1[192*HD + tid];
    bd1sh[tid] = bd1[tid];
    bf2sh[tid] = bf2[tid];
  }
  __syncthreads();

  // ================= encoder =================
  #pragma unroll
  for (int quad = 0; quad < 4; ++quad) {
    unsigned int pw[4];
    #pragma unroll
    for (int jj = 0; jj < 8; jj += 2) {
      const int k = 32*w + 8*quad + jj;
      const float sA = be1[k]   + x0v*We1[k]   + x1v*We1[HD+k]   + yv*We1[2*HD+k];
      const float sB = be1[k+1] + x0v*We1[k+1] + x1v*We1[HD+k+1] + yv*We1[2*HD+k+1];
      pw[jj>>1] = cvtpk(sA*sigf(sA), sB*sigf(sB));
    }
    uint4 v4; v4.x = pw[0]; v4.y = pw[1]; v4.z = pw[2]; v4.w = pw[3];
    ((uint4*)h1f)[(w*4 + (lane>>4))*64 + quad*16 + (lane&15)] = v4;
  }
  __syncthreads();

  // enc L2 (MFMA) -> tau (in h1f), pair-processed
  {
    bh8 af[4];
    #pragma unroll
    for (int kc = 0; kc < 4; ++kc)
      af[kc] = ((const bh8*)h1f)[(kc*4 + w)*64 + lane];
    #pragma unroll 1
    for (int np = 0; np < 4; ++np) {
      const int nt0 = 2*np, nt1 = 2*np + 1;
      const bh8 a0 = We2f[(0*8+nt0)*64 + lane];
      const bh8 a1 = We2f[(1*8+nt0)*64 + lane];
      const bh8 a2 = We2f[(2*8+nt0)*64 + lane];
      const bh8 a3 = We2f[(3*8+nt0)*64 + lane];
      const bh8 c0 = We2f[(0*8+nt1)*64 + lane];
      const bh8 c1 = We2f[(1*8+nt1)*64 + lane];
      const bh8 c2 = We2f[(2*8+nt1)*64 + lane];
      const bh8 c3 = We2f[(3*8+nt1)*64 + lane];
      const float bv0 = f1sh[nt0*16 + rr], bv1 = f1sh[nt1*16 + rr];
      fx4 acc0 = (fx4){bv0, bv0, bv0, bv0};
      fx4 acc1 = (fx4){bv1, bv1, bv1, bv1};
      acc0 = __builtin_amdgcn_mfma_f32_16x16x32_bf16(af[0], a0, acc0, 0,0,0);
      acc1 = __builtin_amdgcn_mfma_f32_16x16x32_bf16(af[0], c0, acc1, 0,0,0);
      acc0 = __builtin_amdgcn_mfma_f32_16x16x32_bf16(af[1], a1, acc0, 0,0,0);
      acc1 = __builtin_amdgcn_mfma_f32_16x16x32_bf16(af[1], c1, acc1, 0,0,0);
      acc0 = __builtin_amdgcn_mfma_f32_16x16x32_bf16(af[2], a2, acc0, 0,0,0);
      acc1 = __builtin_amdgcn_mfma_f32_16x16x32_bf16(af[2], c2, acc1, 0,0,0);
      acc0 = __builtin_amdgcn_mfma_f32_16x16x32_bf16(af[3], a3, acc0, 0,0,0);
      acc1 = __builtin_amdgcn_mfma_f32_16x16x32_bf16(af[3], c3, acc1, 0,0,0);
      #pragma unroll
      for (int pi = 0; pi < 2; ++pi) {
        const int nt = pi ? nt1 : nt0;
        const fx4 acc = pi ? acc1 : acc0;
        #pragma unroll
        for (int g = 0; g < 4; ++g) {
          const float s2 = acc[g];
          const float tf = s2 * sigf(s2);
          const float pf = __shfl_xor(tf, 1, 64);
          if ((rr & 1) == 0) {
            const int unit = ((nt>>1)*4 + w)*64 + (2*(nt&1) + (rr>>3))*16 + 4*qq + g;
            h1f[unit*4 + ((rr&7)>>1)] = cvtpk(tf, pf);
          }
        }
      }
    }
  }
  wave_sync();

  // enc L3 (MFMA) + masked mean-pool -> rsh
  {
    float mkq0, mkq1, mkq2, mkq3;
    {
      const int s0 = (w << 4) | (qq << 2);
      mkq0 = mksh[s0+0]; mkq1 = mksh[s0+1]; mkq2 = mksh[s0+2]; mkq3 = mksh[s0+3];
    }
    bh8 tf4[4];
    #pragma unroll
    for (int kc = 0; kc < 4; ++kc)
      tf4[kc] = ((const bh8*)h1f)[(kc*4 + w)*64 + lane];
    #pragma unroll 1
    for (int np = 0; np < 4; ++np) {
      const int nt0 = 2*np, nt1 = 2*np + 1;
      const bh8 a0 = We3f[(0*8+nt0)*64 + lane];
      const bh8 a1 = We3f[(1*8+nt0)*64 + lane];
      const bh8 a2 = We3f[(2*8+nt0)*64 + lane];
      const bh8 a3 = We3f[(3*8+nt0)*64 + lane];
      const bh8 c0 = We3f[(0*8+nt1)*64 + lane];
      const bh8 c1 = We3f[(1*8+nt1)*64 + lane];
      const bh8 c2 = We3f[(2*8+nt1)*64 + lane];
      const bh8 c3 = We3f[(3*8+nt1)*64 + lane];
      const float bv0 = f2sh[nt0*16 + rr], bv1 = f2sh[nt1*16 + rr];
      fx4 acc0 = (fx4){bv0, bv0, bv0, bv0};
      fx4 acc1 = (fx4){bv1, bv1, bv1, bv1};
      acc0 = __builtin_amdgcn_mfma_f32_16x16x32_bf16(tf4[0], a0, acc0, 0,0,0);
      acc1 = __builtin_amdgcn_mfma_f32_16x16x32_bf16(tf4[0], c0, acc1, 0,0,0);
      acc0 = __builtin_amdgcn_mfma_f32_16x16x32_bf16(tf4[1], a1, acc0, 0,0,0);
      acc1 = __builtin_amdgcn_mfma_f32_16x16x32_bf16(tf4[1], c1, acc1, 0,0,0);
      acc0 = __builtin_amdgcn_mfma_f32_16x16x32_bf16(tf4[2], a2, acc0, 0,0,0);
      acc1 = __builtin_amdgcn_mfma_f32_16x16x32_bf16(tf4[2], c2, acc1, 0,0,0);
      acc0 = __builtin_amdgcn_mfma_f32_16x16x32_bf16(tf4[3], a3, acc0, 0,0,0);
      acc1 = __builtin_amdgcn_mfma_f32_16x16x32_bf16(tf4[3], c3, acc1, 0,0,0);
      #pragma unroll
      for (int pi = 0; pi < 2; ++pi) {
        const int nt = pi ? nt1 : nt0;
        const fx4 acc = pi ? acc1 : acc0;
        float pv = mkq0*acc[0] + mkq1*acc[1] + mkq2*acc[2] + mkq3*acc[3];
        pv += __shfl_xor(pv, 16, 64);
        pv += __shfl_xor(pv, 32, 64);
        if (lane < 16) dsumP[w*128 + nt*16 + lane] = pv;
      }
    }
  }
  __syncthreads();
  if (tid < 128)
    rsh[tid] = (dsumP[tid] + dsumP[128+tid] + dsumP[256+tid] + dsumP[384+tid]) * inv_msum;
  __syncthreads();

  // rW1 precompute (once): rw1sh = bf1 + r @ Wf1_r
  if (tid < 128) {
    float p0 = bf1[tid], p1 = 0.f, p2 = 0.f, p3 = 0.f;
    #pragma unroll 4
    for (int j = 0; j < 128; j += 4) {
      p0 = fmaf(rsh[j+0], Wf1[(64+j+0)*HD + tid], p0);
      p1 = fmaf(rsh[j+1], Wf1[(64+j+1)*HD + tid], p1);
      p2 = fmaf(rsh[j+2], Wf1[(64+j+2)*HD + tid], p2);
      p3 = fmaf(rsh[j+3], Wf1[(64+j+3)*HD + tid], p3);
    }
    rw1sh[tid] = (p0+p1) + (p2+p3);
  }
  __syncthreads();

  // ================= Langevin step loop =================
  for (int st = 0; st < steps; ++st) {
    const float t = (float)st * dt;
    const int zi = tid & 63;

    const float noise_v = noises[(size_t)st * (B_TOT * ZD) + b * ZD + zi];
    const float zold_r  = zsh[zi];

    // ---- A (intra-wave split): wave w lanes 0-31 -> zw1[32w+ln],
    //      lanes 32-63 -> f1sh[32w+ln-32]. Same 64 scalar fmaf per lane.
    {
      const int col = 32*w + (lane & 31);
      const bool isz = (lane < 32);
      const float* Wbase = isz ? Wd1 : Wf1;
      float p0 = isz ? bd1sh[col] : fmaf(t, wt1sh[col], rw1sh[col]);
      float p1 = 0.f, p2 = 0.f, p3 = 0.f;
      #pragma unroll 4
      for (int j = 0; j < 64; j += 4) {
        p0 = fmaf(zsh[j+0], Wbase[(j+0)*HD + col], p0);
        p1 = fmaf(zsh[j+1], Wbase[(j+1)*HD + col], p1);
        p2 = fmaf(zsh[j+2], Wbase[(j+2)*HD + col], p2);
        p3 = fmaf(zsh[j+3], Wbase[(j+3)*HD + col], p3);
      }
      const float a = (p0+p1) + (p2+p3);
      if (isz) zw1[col] = a;
      else     f1sh[col] = a * sigf(a);
    }
    wave_sync();   // B0': dec-L1 (kc=w) reads only zw1[32w..32w+32) (own wave)

    // ---- B: dec L1 on ALL 4 waves (kc = w)
    #pragma unroll
    for (int quad = 0; quad < 4; ++quad) {
      unsigned int pw[4];
      #pragma unroll
      for (int jj = 0; jj < 8; jj += 2) {
        const int k = 32*w + 8*quad + jj;
        const float sA = zw1[k]   + x0v*wx0sh[k]   + x1v*wx1sh[k];
        const float sB = zw1[k+1] + x0v*wx0sh[k+1] + x1v*wx1sh[k+1];
        pw[jj>>1] = cvtpk(sA*sigf(sA), sB*sigf(sB));
      }
      uint4 v4; v4.x = pw[0]; v4.y = pw[1]; v4.z = pw[2]; v4.w = pw[3];
      ((uint4*)h1f)[(w*4 + (lane>>4))*64 + quad*16 + (lane&15)] = v4;
    }
    __syncthreads();   // B1: h1f (all kc) + f1sh + zw1 globally visible

    // fwd (MFMA): S2 = H1 @ Wd2 + bd2; emit tau (wave-private slots)
    float ebw[4];
    {
      bh8 af[4];
      #pragma unroll
      for (int kc = 0; kc < 4; ++kc)
        af[kc] = ((const bh8*)h1f)[(kc*4 + w)*64 + lane];
      float da[4] = {0.f, 0.f, 0.f, 0.f};
      #pragma unroll 1
      for (int np = 0; np < 4; ++np) {
        const int nt0 = 2*np, nt1 = 2*np + 1;
        const bh8 a0 = Wd2f[(0*8+nt0)*64 + lane];
        const bh8 a1 = Wd2f[(1*8+nt0)*64 + lane];
        const bh8 a2 = Wd2f[(2*8+nt0)*64 + lane];
        const bh8 a3 = Wd2f[(3*8+nt0)*64 + lane];
        const bh8 c0 = Wd2f[(0*8+nt1)*64 + lane];
        const bh8 c1 = Wd2f[(1*8+nt1)*64 + lane];
        const bh8 c2 = Wd2f[(2*8+nt1)*64 + lane];
        const bh8 c3 = Wd2f[(3*8+nt1)*64 + lane];
        const float bv0 = bd2sh[nt0*16 + rr], bv1 = bd2sh[nt1*16 + rr];
        fx4 acc0 = (fx4){bv0, bv0, bv0, bv0};
        fx4 acc1 = (fx4){bv1, bv1, bv1, bv1};
        acc0 = __builtin_amdgcn_mfma_f32_16x16x32_bf16(af[0], a0, acc0, 0,0,0);
        acc1 = __builtin_amdgcn_mfma_f32_16x16x32_bf16(af[0], c0, acc1, 0,0,0);
        acc0 = __builtin_amdgcn_mfma_f32_16x16x32_bf16(af[1], a1, acc0, 0,0,0);
        acc1 = __builtin_amdgcn_mfma_f32_16x16x32_bf16(af[1], c1, acc1, 0,0,0);
        acc0 = __builtin_amdgcn_mfma_f32_16x16x32_bf16(af[2], a2, acc0, 0,0,0);
        acc1 = __builtin_amdgcn_mfma_f32_16x16x32_bf16(af[2], c2, acc1, 0,0,0);
        acc0 = __builtin_amdgcn_mfma_f32_16x16x32_bf16(af[3], a3, acc0, 0,0,0);
        acc1 = __builtin_amdgcn_mfma_f32_16x16x32_bf16(af[3], c3, acc1, 0,0,0);
        #pragma unroll
        for (int pi = 0; pi < 2; ++pi) {
          const int nt = pi ? nt1 : nt0;
          const fx4 acc = pi ? acc1 : acc0;
          const float w3 = wd3sh[nt*16 + rr];
          #pragma unroll
          for (int g = 0; g < 4; ++g) {
            const float s2 = acc[g];
            const float sg = sigf(s2);
            da[g] = fmaf(s2*sg, w3, da[g]);
            const float tf = w3 * (sg * fmaf(s2, 1.0f - sg, 1.0f));
            const float pf = __shfl_xor(tf, 1, 64);
            if ((rr & 1) == 0) {
              const int unit = ((nt>>1)*4 + w)*64 + (2*(nt&1) + (rr>>3))*16 + 4*qq + g;
              h1f[unit*4 + ((rr&7)>>1)] = cvtpk(tf, pf);
            }
          }
        }
      }
      const int s0 = (w << 4) | (qq << 2);
      #pragma unroll
      for (int g = 0; g < 4; ++g) {
        float v = da[g];
        v += __shfl_xor(v, 1, 64);
        v += __shfl_xor(v, 2, 64);
        v += __shfl_xor(v, 4, 64);
        v += __shfl_xor(v, 8, 64);
        ebw[g] = t * mksh[s0+g] * (v + bd3v - ysh[s0+g]);
      }
    }
    wave_sync();

    // bwd (MFMA): U = TAU @ Wd2^T; dsum[k] = colsum(ebw * silu'(s1) * U)
    {
      bh8 tf4[4];
      #pragma unroll
      for (int kc = 0; kc < 4; ++kc)
        tf4[kc] = ((const bh8*)h1f)[(kc*4 + w)*64 + lane];
      #pragma unroll 1
      for (int np = 0; np < 4; ++np) {
        const int nt0 = 2*np, nt1 = 2*np + 1;
        const bh8 a0 = Wd2Tf[(0*8+nt0)*64 + lane];
        const bh8 a1 = Wd2Tf[(1*8+nt0)*64 + lane];
        const bh8 a2 = Wd2Tf[(2*8+nt0)*64 + lane];
        const bh8 a3 = Wd2Tf[(3*8+nt0)*64 + lane];
        const bh8 c0 = Wd2Tf[(0*8+nt1)*64 + lane];
        const bh8 c1 = Wd2Tf[(1*8+nt1)*64 + lane];
        const bh8 c2 = Wd2Tf[(2*8+nt1)*64 + lane];
        const bh8 c3 = Wd2Tf[(3*8+nt1)*64 + lane];
        fx4 u0 = (fx4){0.f, 0.f, 0.f, 0.f};
        fx4 u1 = (fx4){0.f, 0.f, 0.f, 0.f};
        u0 = __builtin_amdgcn_mfma_f32_16x16x32_bf16(tf4[0], a0, u0, 0,0,0);
        u1 = __builtin_amdgcn_mfma_f32_16x16x32_bf16(tf4[0], c0, u1, 0,0,0);
        u0 = __builtin_amdgcn_mfma_f32_16x16x32_bf16(tf4[1], a1, u0, 0,0,0);
        u1 = __builtin_amdgcn_mfma_f32_16x16x32_bf16(tf4[1], c1, u1, 0,0,0);
        u0 = __builtin_amdgcn_mfma_f32_16x16x32_bf16(tf4[2], a2, u0, 0,0,0);
        u1 = __builtin_amdgcn_mfma_f32_16x16x32_bf16(tf4[2], c2, u1, 0,0,0);
        u0 = __builtin_amdgcn_mfma_f32_16x16x32_bf16(tf4[3], a3, u0, 0,0,0);
        u1 = __builtin_amdgcn_mfma_f32_16x16x32_bf16(tf4[3], c3, u1, 0,0,0);
        #pragma unroll
        for (int pi = 0; pi < 2; ++pi) {
          const int nt = pi ? nt1 : nt0;
          const fx4 u = pi ? u1 : u0;
          const float zv = zw1[nt*16 + rr];
          const float wa = wx0sh[nt*16 + rr];
          const float wb = wx1sh[nt*16 + rr];
          float snt = 0.f;
          #pragma unroll
          for (int g = 0; g < 4; ++g) {
            const float s1 = zv + x0q[g]*wa + x1q[g]*wb;
            const float sg = sigf(s1);
            snt += ebw[g] * (sg * fmaf(s1, 1.0f - sg, 1.0f)) * u[g];
          }
          snt += __shfl_xor(snt, 16, 64);
          snt += __shfl_xor(snt, 32, 64);
          if (lane < 16) dsumP[w*128 + nt*16 + lane] = snt;
        }
      }
    }
    __syncthreads();   // B3: dsumP ready (zw1 now dead -> scratch)

    // ---- S3 (balanced): t<128: dsumC combine + f2 partial j=64..127 -> rsh
    //                     t>=128: f2 partial j=0..63 (+bf2) -> zw1
    if (tid < 128) {
      dsumC[tid] = dsumP[tid] + dsumP[128+tid] + dsumP[256+tid] + dsumP[384+tid];
      float p0 = 0.f, p1 = 0.f, p2 = 0.f, p3 = 0.f;
      #pragma unroll 4
      for (int j = 64; j < 128; j += 4) {
        p0 = fmaf(f1sh[j+0], Wf2[(j+0)*HD + tid], p0);
        p1 = fmaf(f1sh[j+1], Wf2[(j+1)*HD + tid], p1);
        p2 = fmaf(f1sh[j+2], Wf2[(j+2)*HD + tid], p2);
        p3 = fmaf(f1sh[j+3], Wf2[(j+3)*HD + tid], p3);
      }
      rsh[tid] = (p0+p1) + (p2+p3);
    } else {
      const int o = tid - 128;
      float p0 = bf2sh[o], p1 = 0.f, p2 = 0.f, p3 = 0.f;
      #pragma unroll 4
      for (int j = 0; j < 64; j += 4) {
        p0 = fmaf(f1sh[j+0], Wf2[(j+0)*HD + o], p0);
        p1 = fmaf(f1sh[j+1], Wf2[(j+1)*HD + o], p1);
        p2 = fmaf(f1sh[j+2], Wf2[(j+2)*HD + o], p2);
        p3 = fmaf(f1sh[j+3], Wf2[(j+3)*HD + o], p3);
      }
      zw1[o] = (p0+p1) + (p2+p3);
    }
    __syncthreads();   // B4: dsumC + f2 partials ready (cross-wave rsh/zw1)

    // ---- S4: t<128: gz halves (Wd1T, coalesced) -> dsumP
    //          t>=128: f2 combine+silu (wave-local), wave_sync, f3 -> bgz
    if (tid < 128) {
      const int j = tid & 63, h0 = (tid >> 6) * 64;
      float p0 = 0.f, p1 = 0.f, p2 = 0.f, p3 = 0.f;
      #pragma unroll 4
      for (int h = 0; h < 64; h += 4) {
        p0 = fmaf(dsumC[h0+h+0], Wd1T[(h0+h+0)*64 + j], p0);
        p1 = fmaf(dsumC[h0+h+1], Wd1T[(h0+h+1)*64 + j], p1);
        p2 = fmaf(dsumC[h0+h+2], Wd1T[(h0+h+2)*64 + j], p2);
        p3 = fmaf(dsumC[h0+h+3], Wd1T[(h0+h+3)*64 + j], p3);
      }
      dsumP[tid] = (p0+p1) + (p2+p3);            // gz partials (t in ebw)
    } else {
      const int o = tid - 128;
      const float a = rsh[o] + zw1[o];
      f2sh[o] = a * sigf(a);                     // own-wave slot (64/wave)
      wave_sync();                               // f2sh half visible in-wave
      const int j = o & 63, h0 = (o >> 6) * 64;  // reads own wave's half
      float p0 = (h0 == 0) ? bf3sh[j] : 0.f;
      float p1 = 0.f, p2 = 0.f, p3 = 0.f;
      #pragma unroll 4
      for (int h = 0; h < 64; h += 4) {
        p0 = fmaf(f2sh[h0+h+0], Wf3[(h0+h+0)*ZD + j], p0);
        p1 = fmaf(f2sh[h0+h+1], Wf3[(h0+h+1)*ZD + j], p1);
        p2 = fmaf(f2sh[h0+h+2], Wf3[(h0+h+2)*ZD + j], p2);
        p3 = fmaf(f2sh[h0+h+3], Wf3[(h0+h+3)*ZD + j], p3);
      }
      bgz[o] = (p0+p1) + (p2+p3);                // f3 partials
    }
    __syncthreads();   // B5: partials ready (cross-wave reads next)

    // ---- update: redundant on ALL waves; zold from step-top register.
    {
      const float bdrift = bgz[zi] + bgz[64 + zi];
      const float gzv    = dsumP[zi] + dsumP[64 + zi];
      float g = zold_r + gzv;
      g = fminf(fmaxf(g, -100.0f), 100.0f);
      zsh[zi] = zold_r + (bdrift - g) * dt + dco * noise_v;
    }
    wave_sync();       // own-wave zsh writes drained
  }

  if (tid < 64) out[b * ZD + tid] = zsh[tid];
}

extern "C" void kernel_launch(void* const* d_in, const int* in_sizes, int n_in,
                              void* d_out, int out_size, void* d_ws, size_t ws_size,
                              hipStream_t stream) {
  const float* x_ctx  = (const float*)d_in[0];
  const float* y_ctx  = (const float*)d_in[1];
  const float* mask   = (const float*)d_in[2];
  const float* z0     = (const float*)d_in[3];
  const float* noises = (const float*)d_in[4];
  const float* We1 = (const float*)d_in[5];  const float* be1 = (const float*)d_in[6];
  const float* We2 = (const float*)d_in[7];  const float* be2 = (const float*)d_in[8];
  const float* We3 = (const float*)d_in[9];  const float* be3 = (const float*)d_in[10];
  const float* Wd1 = (const float*)d_in[11]; const float* bd1 = (const float*)d_in[12];
  const float* Wd2 = (const float*)d_in[13]; const float* bd2 = (const float*)d_in[14];
  const float* Wd3 = (const float*)d_in[15]; const float* bd3 = (const float*)d_in[16];
  const float* Wf1 = (const float*)d_in[17]; const float* bf1 = (const float*)d_in[18];
  const float* Wf2 = (const float*)d_in[19]; const float* bf2 = (const float*)d_in[20];
  const float* Wf3 = (const float*)d_in[21]; const float* bf3 = (const float*)d_in[22];

  const int steps = in_sizes[4] / (B_TOT * ZD);
  const float dt  = 1.0f / (float)steps;
  const float dco = (float)sqrt(2.0 / (double)steps);

  ushort* wsu = (ushort*)d_ws;   // 128KB frag arrays + 32KB Wd1T

  hipLaunchKernelGGL(prep_kernel, dim3(288), dim3(256), 0, stream,
                     Wd2, We2, We3, Wd1, wsu);
  hipLaunchKernelGGL(metanets_kernel, dim3(B_TOT), dim3(256), 0, stream,
      x_ctx, y_ctx, mask, z0, noises,
      We1, be1, be2, be3,
      Wd1, bd1, bd2, Wd3, bd3,
      Wf1, bf1, Wf2, bf2, Wf3, bf3,
      wsu, (float*)d_out, steps, dt, dco);
}

// Round 16
// 825.625 us; speedup vs baseline: 1.3172x; 1.3172x over previous
//
#include <hip/hip_runtime.h>
#include <math.h>

// MetaNETS Langevin sampler, MI355X — round 21: REVERT to R19 (best, 829.5us).
// R20 post-mortem (regressed 829->1088): the intra-wave phase-A remap alone
// spills — divergent per-lane-half weight base (Wd1 vs Wf1) defeats
// SGPR-folded addressing, WRITE_SIZE 2.6->64.5MB. Both R17 components now
// individually rejected (pk: stalls, R18; remap: spills, R20).
// This kernel = R19 verbatim: R16 structure + bd1/bf2/bf3 LDS staging.
// Accepted ladder: wave-role overlap (R8), pair-processed MFMA + (256,4)
// register diet -> 4-wave bin (R10), balanced phase A + race-safe redundant
// z-update (R11/12), balanced S3/S4 (R14), Wd1T-coalesced gz (R15),
// cvt_pk + ysh/mksh reg relief (R16), bias LDS staging (R19).

#define B_TOT 2048
#define NPT   64
#define ZD    64
#define HD    128

typedef short bh8 __attribute__((ext_vector_type(8)));   // 8 x bf16 (4 VGPR)
typedef float fx4 __attribute__((ext_vector_type(4)));   // MFMA C/D

__device__ __forceinline__ float sigf(float x) {
  return __builtin_amdgcn_rcpf(1.0f + __expf(-x));
}
__device__ __forceinline__ unsigned int bfb(float x) {   // fp32 -> bf16 bits (RNE)
  unsigned int u = __float_as_uint(x);
  u += 0x7FFFu + ((u >> 16) & 1u);
  return u >> 16;
}
__device__ __forceinline__ unsigned int cvtpk(float a, float b) {
  unsigned int r;
  asm("v_cvt_pk_bf16_f32 %0, %1, %2" : "=v"(r) : "v"(a), "v"(b));
  return r;
}
__device__ __forceinline__ float wsum64(float v) {
  #pragma unroll
  for (int d = 1; d < 64; d <<= 1) v += __shfl_xor(v, d, 64);
  return v;
}
__device__ __forceinline__ void wave_sync() {   // intra-wave LDS order + drain
  __builtin_amdgcn_wave_barrier();
  __builtin_amdgcn_s_waitcnt(0xC07F);           // lgkmcnt(0)
  __builtin_amdgcn_wave_barrier();
}

// ws layout: [0,128KB): 4 bf16 B-frag arrays (Wd2, Wd2^T, We2, We3);
//            [128KB,160KB): Wd1T fp32 (Wd1T[h][j] = Wd1[j][h], 128x64).
// B-frag: frag[((kc*8+nt)*64 + L)*8 + j] = W[kc*32 + (L>>4)*8 + j][nt*16 + (L&15)]
__global__ __launch_bounds__(256)
void prep_kernel(const float* __restrict__ Wd2, const float* __restrict__ We2,
                 const float* __restrict__ We3, const float* __restrict__ Wd1,
                 ushort* __restrict__ ws) {
  const int id = blockIdx.x * 256 + threadIdx.x;   // 73728 total
  if (id < 65536) {
    const int arr = id >> 14;
    const int e = id & 16383;
    const int j = e & 7, L = (e >> 3) & 63, nt = (e >> 9) & 7, kc = e >> 12;
    const int kk = kc * 32 + (L >> 4) * 8 + j, nn = nt * 16 + (L & 15);
    float v;
    if      (arr == 0) v = Wd2[kk * HD + nn];
    else if (arr == 1) v = Wd2[nn * HD + kk];    // Wd2^T
    else if (arr == 2) v = We2[kk * HD + nn];
    else               v = We3[kk * HD + nn];
    ws[id] = (ushort)bfb(v);
  } else {
    const int e = id - 65536;                    // [0, 8192)
    const int h = e >> 6, jj = e & 63;
    ((float*)(ws + 65536))[e] = Wd1[jj * HD + h];
  }
}

__global__ __launch_bounds__(256, 4)
void metanets_kernel(
    const float* __restrict__ x_ctx, const float* __restrict__ y_ctx,
    const float* __restrict__ mask,  const float* __restrict__ z0,
    const float* __restrict__ noises,
    const float* __restrict__ We1, const float* __restrict__ be1,
    const float* __restrict__ be2, const float* __restrict__ be3,
    const float* __restrict__ Wd1, const float* __restrict__ bd1,
    const float* __restrict__ bd2, const float* __restrict__ Wd3,
    const float* __restrict__ bd3,
    const float* __restrict__ Wf1, const float* __restrict__ bf1,
    const float* __restrict__ Wf2, const float* __restrict__ bf2,
    const float* __restrict__ Wf3, const float* __restrict__ bf3,
    const ushort* __restrict__ wsfrag,
    float* __restrict__ out, int steps, float dt, float dco)
{
  // h1f doubles as the tau buffer (R7 invariant): within fwd/bwd every wave
  // touches only slots == w (mod 4) and A-frags are reg-loaded before the tau
  // scatter overwrites them.
  __shared__ unsigned int h1f[4096];    // A-frag units: [(slot)*64 + lane] x 4 dw
  __shared__ float zsh[64];
  __shared__ float zw1[128];            // dec-L1 pre-act; f2-partial scratch in S3
  __shared__ float rsh[128];            // encoder r; f2-partial scratch in-loop
  __shared__ float dsumP[512];
  __shared__ float dsumC[128];
  __shared__ float f1sh[128];           // be2 staging, then drift hidden1
  __shared__ float f2sh[128];           // be3 staging, then drift hidden2
  __shared__ float bgz[128];            // f3 k-split partials (2x64)
  __shared__ float rw1sh[128];          // bf1 + r @ Wf1_r (step-invariant)
  __shared__ float wt1sh[128];          // Wf1 t-row staged
  __shared__ float ysh[64], mksh[64];   // y/mask per point (reg relief)
  __shared__ float bd1sh[128];          // bd1 staged (phase-A chain)
  __shared__ float bf2sh[128];          // bf2 staged (S3 chain)
  __shared__ float bf3sh[64];           // bf3 staged (S4 chain)
  __shared__ float bd2sh[128], wd3sh[128], wx0sh[128], wx1sh[128];

  const int tid = threadIdx.x;
  const int lane = tid & 63;                                  // context point
  const int w = __builtin_amdgcn_readfirstlane(tid >> 6);     // wave = m-tile
  const int b = blockIdx.x;
  const int rr = lane & 15, qq = lane >> 4;

  const bh8* Wd2f  = (const bh8*)(wsfrag);
  const bh8* Wd2Tf = (const bh8*)(wsfrag + 16384);
  const bh8* We2f  = (const bh8*)(wsfrag + 32768);
  const bh8* We3f  = (const bh8*)(wsfrag + 49152);
  const float* Wd1T = (const float*)(wsfrag + 65536);   // [128][64] fp32

  const float x0v = x_ctx[(b*NPT + lane)*2 + 0];
  const float x1v = x_ctx[(b*NPT + lane)*2 + 1];
  const float yv  = y_ctx[b*NPT + lane];
  const float mkv = mask[b*NPT + lane];
  const float inv_msum = 1.0f / fmaxf(wsum64(mkv), 1e-6f);
  const float bd3v = bd3[0];

  float x0q[4], x1q[4];
  #pragma unroll
  for (int g = 0; g < 4; ++g) {
    const int src = (w << 4) | (qq << 2) | g;
    x0q[g] = __shfl(x0v, src, 64);
    x1q[g] = __shfl(x1v, src, 64);
  }

  if (tid < 64) {
    zsh[tid]  = z0[b*ZD + tid];
    ysh[tid]  = yv;
    mksh[tid] = mkv;
    bf3sh[tid] = bf3[tid];
  }
  if (tid < 128) {
    bd2sh[tid] = bd2[tid];
    wd3sh[tid] = Wd3[tid];
    wx0sh[tid] = Wd1[64*HD + tid];
    wx1sh[tid] = Wd1[65*HD + tid];
    f1sh[tid]  = be2[tid];
    f2sh[tid]  = be3[tid];
    wt1sh[tid] = Wf1[192*HD + tid];
    bd1sh[tid] = bd1[tid];
    bf2sh[tid] = bf2[tid];
  }
  __syncthreads();

  // ================= encoder =================
  #pragma unroll
  for (int quad = 0; quad < 4; ++quad) {
    unsigned int pw[4];
    #pragma unroll
    for (int jj = 0; jj < 8; jj += 2) {
      const int k = 32*w + 8*quad + jj;
      const float sA = be1[k]   + x0v*We1[k]   + x1v*We1[HD+k]   + yv*We1[2*HD+k];
      const float sB = be1[k+1] + x0v*We1[k+1] + x1v*We1[HD+k+1] + yv*We1[2*HD+k+1];
      pw[jj>>1] = cvtpk(sA*sigf(sA), sB*sigf(sB));
    }
    uint4 v4; v4.x = pw[0]; v4.y = pw[1]; v4.z = pw[2]; v4.w = pw[3];
    ((uint4*)h1f)[(w*4 + (lane>>4))*64 + quad*16 + (lane&15)] = v4;
  }
  __syncthreads();

  // enc L2 (MFMA) -> tau (in h1f), pair-processed
  {
    bh8 af[4];
    #pragma unroll
    for (int kc = 0; kc < 4; ++kc)
      af[kc] = ((const bh8*)h1f)[(kc*4 + w)*64 + lane];
    #pragma unroll 1
    for (int np = 0; np < 4; ++np) {
      const int nt0 = 2*np, nt1 = 2*np + 1;
      const bh8 a0 = We2f[(0*8+nt0)*64 + lane];
      const bh8 a1 = We2f[(1*8+nt0)*64 + lane];
      const bh8 a2 = We2f[(2*8+nt0)*64 + lane];
      const bh8 a3 = We2f[(3*8+nt0)*64 + lane];
      const bh8 c0 = We2f[(0*8+nt1)*64 + lane];
      const bh8 c1 = We2f[(1*8+nt1)*64 + lane];
      const bh8 c2 = We2f[(2*8+nt1)*64 + lane];
      const bh8 c3 = We2f[(3*8+nt1)*64 + lane];
      const float bv0 = f1sh[nt0*16 + rr], bv1 = f1sh[nt1*16 + rr];
      fx4 acc0 = (fx4){bv0, bv0, bv0, bv0};
      fx4 acc1 = (fx4){bv1, bv1, bv1, bv1};
      acc0 = __builtin_amdgcn_mfma_f32_16x16x32_bf16(af[0], a0, acc0, 0,0,0);
      acc1 = __builtin_amdgcn_mfma_f32_16x16x32_bf16(af[0], c0, acc1, 0,0,0);
      acc0 = __builtin_amdgcn_mfma_f32_16x16x32_bf16(af[1], a1, acc0, 0,0,0);
      acc1 = __builtin_amdgcn_mfma_f32_16x16x32_bf16(af[1], c1, acc1, 0,0,0);
      acc0 = __builtin_amdgcn_mfma_f32_16x16x32_bf16(af[2], a2, acc0, 0,0,0);
      acc1 = __builtin_amdgcn_mfma_f32_16x16x32_bf16(af[2], c2, acc1, 0,0,0);
      acc0 = __builtin_amdgcn_mfma_f32_16x16x32_bf16(af[3], a3, acc0, 0,0,0);
      acc1 = __builtin_amdgcn_mfma_f32_16x16x32_bf16(af[3], c3, acc1, 0,0,0);
      #pragma unroll
      for (int pi = 0; pi < 2; ++pi) {
        const int nt = pi ? nt1 : nt0;
        const fx4 acc = pi ? acc1 : acc0;
        #pragma unroll
        for (int g = 0; g < 4; ++g) {
          const float s2 = acc[g];
          const float tf = s2 * sigf(s2);
          const float pf = __shfl_xor(tf, 1, 64);
          if ((rr & 1) == 0) {
            const int unit = ((nt>>1)*4 + w)*64 + (2*(nt&1) + (rr>>3))*16 + 4*qq + g;
            h1f[unit*4 + ((rr&7)>>1)] = cvtpk(tf, pf);
          }
        }
      }
    }
  }
  wave_sync();

  // enc L3 (MFMA) + masked mean-pool -> rsh
  {
    float mkq0, mkq1, mkq2, mkq3;
    {
      const int s0 = (w << 4) | (qq << 2);
      mkq0 = mksh[s0+0]; mkq1 = mksh[s0+1]; mkq2 = mksh[s0+2]; mkq3 = mksh[s0+3];
    }
    bh8 tf4[4];
    #pragma unroll
    for (int kc = 0; kc < 4; ++kc)
      tf4[kc] = ((const bh8*)h1f)[(kc*4 + w)*64 + lane];
    #pragma unroll 1
    for (int np = 0; np < 4; ++np) {
      const int nt0 = 2*np, nt1 = 2*np + 1;
      const bh8 a0 = We3f[(0*8+nt0)*64 + lane];
      const bh8 a1 = We3f[(1*8+nt0)*64 + lane];
      const bh8 a2 = We3f[(2*8+nt0)*64 + lane];
      const bh8 a3 = We3f[(3*8+nt0)*64 + lane];
      const bh8 c0 = We3f[(0*8+nt1)*64 + lane];
      const bh8 c1 = We3f[(1*8+nt1)*64 + lane];
      const bh8 c2 = We3f[(2*8+nt1)*64 + lane];
      const bh8 c3 = We3f[(3*8+nt1)*64 + lane];
      const float bv0 = f2sh[nt0*16 + rr], bv1 = f2sh[nt1*16 + rr];
      fx4 acc0 = (fx4){bv0, bv0, bv0, bv0};
      fx4 acc1 = (fx4){bv1, bv1, bv1, bv1};
      acc0 = __builtin_amdgcn_mfma_f32_16x16x32_bf16(tf4[0], a0, acc0, 0,0,0);
      acc1 = __builtin_amdgcn_mfma_f32_16x16x32_bf16(tf4[0], c0, acc1, 0,0,0);
      acc0 = __builtin_amdgcn_mfma_f32_16x16x32_bf16(tf4[1], a1, acc0, 0,0,0);
      acc1 = __builtin_amdgcn_mfma_f32_16x16x32_bf16(tf4[1], c1, acc1, 0,0,0);
      acc0 = __builtin_amdgcn_mfma_f32_16x16x32_bf16(tf4[2], a2, acc0, 0,0,0);
      acc1 = __builtin_amdgcn_mfma_f32_16x16x32_bf16(tf4[2], c2, acc1, 0,0,0);
      acc0 = __builtin_amdgcn_mfma_f32_16x16x32_bf16(tf4[3], a3, acc0, 0,0,0);
      acc1 = __builtin_amdgcn_mfma_f32_16x16x32_bf16(tf4[3], c3, acc1, 0,0,0);
      #pragma unroll
      for (int pi = 0; pi < 2; ++pi) {
        const int nt = pi ? nt1 : nt0;
        const fx4 acc = pi ? acc1 : acc0;
        float pv = mkq0*acc[0] + mkq1*acc[1] + mkq2*acc[2] + mkq3*acc[3];
        pv += __shfl_xor(pv, 16, 64);
        pv += __shfl_xor(pv, 32, 64);
        if (lane < 16) dsumP[w*128 + nt*16 + lane] = pv;
      }
    }
  }
  __syncthreads();
  if (tid < 128)
    rsh[tid] = (dsumP[tid] + dsumP[128+tid] + dsumP[256+tid] + dsumP[384+tid]) * inv_msum;
  __syncthreads();

  // rW1 precompute (once): rw1sh = bf1 + r @ Wf1_r
  if (tid < 128) {
    float p0 = bf1[tid], p1 = 0.f, p2 = 0.f, p3 = 0.f;
    #pragma unroll 4
    for (int j = 0; j < 128; j += 4) {
      p0 = fmaf(rsh[j+0], Wf1[(64+j+0)*HD + tid], p0);
      p1 = fmaf(rsh[j+1], Wf1[(64+j+1)*HD + tid], p1);
      p2 = fmaf(rsh[j+2], Wf1[(64+j+2)*HD + tid], p2);
      p3 = fmaf(rsh[j+3], Wf1[(64+j+3)*HD + tid], p3);
    }
    rw1sh[tid] = (p0+p1) + (p2+p3);
  }
  __syncthreads();

  // ================= Langevin step loop =================
  for (int st = 0; st < steps; ++st) {
    const float t = (float)st * dt;
    const int zi = tid & 63;

    const float noise_v = noises[(size_t)st * (B_TOT * ZD) + b * ZD + zi];
    const float zold_r  = zsh[zi];

    // ---- A: t<128: zw1  ||  t>=128: f1 (both 64-fmaf matvecs, balanced)
    if (tid < 128) {
      float p0 = bd1sh[tid], p1 = 0.f, p2 = 0.f, p3 = 0.f;
      #pragma unroll 4
      for (int j = 0; j < 64; j += 4) {
        p0 = fmaf(zsh[j+0], Wd1[(j+0)*HD + tid], p0);
        p1 = fmaf(zsh[j+1], Wd1[(j+1)*HD + tid], p1);
        p2 = fmaf(zsh[j+2], Wd1[(j+2)*HD + tid], p2);
        p3 = fmaf(zsh[j+3], Wd1[(j+3)*HD + tid], p3);
      }
      zw1[tid] = (p0+p1) + (p2+p3);
    } else {
      const int o = tid - 128;
      float p0 = fmaf(t, wt1sh[o], rw1sh[o]);
      float p1 = 0.f, p2 = 0.f, p3 = 0.f;
      #pragma unroll 4
      for (int j = 0; j < 64; j += 4) {
        p0 = fmaf(zsh[j+0], Wf1[(j+0)*HD + o], p0);
        p1 = fmaf(zsh[j+1], Wf1[(j+1)*HD + o], p1);
        p2 = fmaf(zsh[j+2], Wf1[(j+2)*HD + o], p2);
        p3 = fmaf(zsh[j+3], Wf1[(j+3)*HD + o], p3);
      }
      const float a = (p0+p1) + (p2+p3);
      f1sh[o] = a * sigf(a);
    }
    __syncthreads();   // B0: zw1 + f1sh ready

    // ---- B: dec L1 on ALL 4 waves (kc = w)
    #pragma unroll
    for (int quad = 0; quad < 4; ++quad) {
      unsigned int pw[4];
      #pragma unroll
      for (int jj = 0; jj < 8; jj += 2) {
        const int k = 32*w + 8*quad + jj;
        const float sA = zw1[k]   + x0v*wx0sh[k]   + x1v*wx1sh[k];
        const float sB = zw1[k+1] + x0v*wx0sh[k+1] + x1v*wx1sh[k+1];
        pw[jj>>1] = cvtpk(sA*sigf(sA), sB*sigf(sB));
      }
      uint4 v4; v4.x = pw[0]; v4.y = pw[1]; v4.z = pw[2]; v4.w = pw[3];
      ((uint4*)h1f)[(w*4 + (lane>>4))*64 + quad*16 + (lane&15)] = v4;
    }
    __syncthreads();   // B1: h1f (all kc slices) ready

    // fwd (MFMA): S2 = H1 @ Wd2 + bd2; emit tau (wave-private slots)
    float ebw[4];
    {
      bh8 af[4];
      #pragma unroll
      for (int kc = 0; kc < 4; ++kc)
        af[kc] = ((const bh8*)h1f)[(kc*4 + w)*64 + lane];
      float da[4] = {0.f, 0.f, 0.f, 0.f};
      #pragma unroll 1
      for (int np = 0; np < 4; ++np) {
        const int nt0 = 2*np, nt1 = 2*np + 1;
        const bh8 a0 = Wd2f[(0*8+nt0)*64 + lane];
        const bh8 a1 = Wd2f[(1*8+nt0)*64 + lane];
        const bh8 a2 = Wd2f[(2*8+nt0)*64 + lane];
        const bh8 a3 = Wd2f[(3*8+nt0)*64 + lane];
        const bh8 c0 = Wd2f[(0*8+nt1)*64 + lane];
        const bh8 c1 = Wd2f[(1*8+nt1)*64 + lane];
        const bh8 c2 = Wd2f[(2*8+nt1)*64 + lane];
        const bh8 c3 = Wd2f[(3*8+nt1)*64 + lane];
        const float bv0 = bd2sh[nt0*16 + rr], bv1 = bd2sh[nt1*16 + rr];
        fx4 acc0 = (fx4){bv0, bv0, bv0, bv0};
        fx4 acc1 = (fx4){bv1, bv1, bv1, bv1};
        acc0 = __builtin_amdgcn_mfma_f32_16x16x32_bf16(af[0], a0, acc0, 0,0,0);
        acc1 = __builtin_amdgcn_mfma_f32_16x16x32_bf16(af[0], c0, acc1, 0,0,0);
        acc0 = __builtin_amdgcn_mfma_f32_16x16x32_bf16(af[1], a1, acc0, 0,0,0);
        acc1 = __builtin_amdgcn_mfma_f32_16x16x32_bf16(af[1], c1, acc1, 0,0,0);
        acc0 = __builtin_amdgcn_mfma_f32_16x16x32_bf16(af[2], a2, acc0, 0,0,0);
        acc1 = __builtin_amdgcn_mfma_f32_16x16x32_bf16(af[2], c2, acc1, 0,0,0);
        acc0 = __builtin_amdgcn_mfma_f32_16x16x32_bf16(af[3], a3, acc0, 0,0,0);
        acc1 = __builtin_amdgcn_mfma_f32_16x16x32_bf16(af[3], c3, acc1, 0,0,0);
        #pragma unroll
        for (int pi = 0; pi < 2; ++pi) {
          const int nt = pi ? nt1 : nt0;
          const fx4 acc = pi ? acc1 : acc0;
          const float w3 = wd3sh[nt*16 + rr];
          #pragma unroll
          for (int g = 0; g < 4; ++g) {
            const float s2 = acc[g];
            const float sg = sigf(s2);
            da[g] = fmaf(s2*sg, w3, da[g]);
            const float tf = w3 * (sg * fmaf(s2, 1.0f - sg, 1.0f));
            const float pf = __shfl_xor(tf, 1, 64);
            if ((rr & 1) == 0) {
              const int unit = ((nt>>1)*4 + w)*64 + (2*(nt&1) + (rr>>3))*16 + 4*qq + g;
              h1f[unit*4 + ((rr&7)>>1)] = cvtpk(tf, pf);
            }
          }
        }
      }
      const int s0 = (w << 4) | (qq << 2);
      #pragma unroll
      for (int g = 0; g < 4; ++g) {
        float v = da[g];
        v += __shfl_xor(v, 1, 64);
        v += __shfl_xor(v, 2, 64);
        v += __shfl_xor(v, 4, 64);
        v += __shfl_xor(v, 8, 64);
        ebw[g] = t * mksh[s0+g] * (v + bd3v - ysh[s0+g]);
      }
    }
    wave_sync();

    // bwd (MFMA): U = TAU @ Wd2^T; dsum[k] = colsum(ebw * silu'(s1) * U)
    {
      bh8 tf4[4];
      #pragma unroll
      for (int kc = 0; kc < 4; ++kc)
        tf4[kc] = ((const bh8*)h1f)[(kc*4 + w)*64 + lane];
      #pragma unroll 1
      for (int np = 0; np < 4; ++np) {
        const int nt0 = 2*np, nt1 = 2*np + 1;
        const bh8 a0 = Wd2Tf[(0*8+nt0)*64 + lane];
        const bh8 a1 = Wd2Tf[(1*8+nt0)*64 + lane];
        const bh8 a2 = Wd2Tf[(2*8+nt0)*64 + lane];
        const bh8 a3 = Wd2Tf[(3*8+nt0)*64 + lane];
        const bh8 c0 = Wd2Tf[(0*8+nt1)*64 + lane];
        const bh8 c1 = Wd2Tf[(1*8+nt1)*64 + lane];
        const bh8 c2 = Wd2Tf[(2*8+nt1)*64 + lane];
        const bh8 c3 = Wd2Tf[(3*8+nt1)*64 + lane];
        fx4 u0 = (fx4){0.f, 0.f, 0.f, 0.f};
        fx4 u1 = (fx4){0.f, 0.f, 0.f, 0.f};
        u0 = __builtin_amdgcn_mfma_f32_16x16x32_bf16(tf4[0], a0, u0, 0,0,0);
        u1 = __builtin_amdgcn_mfma_f32_16x16x32_bf16(tf4[0], c0, u1, 0,0,0);
        u0 = __builtin_amdgcn_mfma_f32_16x16x32_bf16(tf4[1], a1, u0, 0,0,0);
        u1 = __builtin_amdgcn_mfma_f32_16x16x32_bf16(tf4[1], c1, u1, 0,0,0);
        u0 = __builtin_amdgcn_mfma_f32_16x16x32_bf16(tf4[2], a2, u0, 0,0,0);
        u1 = __builtin_amdgcn_mfma_f32_16x16x32_bf16(tf4[2], c2, u1, 0,0,0);
        u0 = __builtin_amdgcn_mfma_f32_16x16x32_bf16(tf4[3], a3, u0, 0,0,0);
        u1 = __builtin_amdgcn_mfma_f32_16x16x32_bf16(tf4[3], c3, u1, 0,0,0);
        #pragma unroll
        for (int pi = 0; pi < 2; ++pi) {
          const int nt = pi ? nt1 : nt0;
          const fx4 u = pi ? u1 : u0;
          const float zv = zw1[nt*16 + rr];
          const float wa = wx0sh[nt*16 + rr];
          const float wb = wx1sh[nt*16 + rr];
          float snt = 0.f;
          #pragma unroll
          for (int g = 0; g < 4; ++g) {
            const float s1 = zv + x0q[g]*wa + x1q[g]*wb;
            const float sg = sigf(s1);
            snt += ebw[g] * (sg * fmaf(s1, 1.0f - sg, 1.0f)) * u[g];
          }
          snt += __shfl_xor(snt, 16, 64);
          snt += __shfl_xor(snt, 32, 64);
          if (lane < 16) dsumP[w*128 + nt*16 + lane] = snt;
        }
      }
    }
    __syncthreads();   // B3: dsumP ready (zw1 now dead -> scratch)

    // ---- S3 (balanced): t<128: dsumC combine + f2 partial j=64..127 -> rsh
    //                     t>=128: f2 partial j=0..63 (+bf2) -> zw1
    if (tid < 128) {
      dsumC[tid] = dsumP[tid] + dsumP[128+tid] + dsumP[256+tid] + dsumP[384+tid];
      float p0 = 0.f, p1 = 0.f, p2 = 0.f, p3 = 0.f;
      #pragma unroll 4
      for (int j = 64; j < 128; j += 4) {
        p0 = fmaf(f1sh[j+0], Wf2[(j+0)*HD + tid], p0);
        p1 = fmaf(f1sh[j+1], Wf2[(j+1)*HD + tid], p1);
        p2 = fmaf(f1sh[j+2], Wf2[(j+2)*HD + tid], p2);
        p3 = fmaf(f1sh[j+3], Wf2[(j+3)*HD + tid], p3);
      }
      rsh[tid] = (p0+p1) + (p2+p3);
    } else {
      const int o = tid - 128;
      float p0 = bf2sh[o], p1 = 0.f, p2 = 0.f, p3 = 0.f;
      #pragma unroll 4
      for (int j = 0; j < 64; j += 4) {
        p0 = fmaf(f1sh[j+0], Wf2[(j+0)*HD + o], p0);
        p1 = fmaf(f1sh[j+1], Wf2[(j+1)*HD + o], p1);
        p2 = fmaf(f1sh[j+2], Wf2[(j+2)*HD + o], p2);
        p3 = fmaf(f1sh[j+3], Wf2[(j+3)*HD + o], p3);
      }
      zw1[o] = (p0+p1) + (p2+p3);
    }
    __syncthreads();   // B4: dsumC + f2 partials ready (cross-wave rsh/zw1)

    // ---- S4: t<128: gz halves (Wd1T, coalesced) -> dsumP
    //          t>=128: f2 combine+silu (wave-local), wave_sync, f3 -> bgz
    if (tid < 128) {
      const int j = tid & 63, h0 = (tid >> 6) * 64;
      float p0 = 0.f, p1 = 0.f, p2 = 0.f, p3 = 0.f;
      #pragma unroll 4
      for (int h = 0; h < 64; h += 4) {
        p0 = fmaf(dsumC[h0+h+0], Wd1T[(h0+h+0)*64 + j], p0);
        p1 = fmaf(dsumC[h0+h+1], Wd1T[(h0+h+1)*64 + j], p1);
        p2 = fmaf(dsumC[h0+h+2], Wd1T[(h0+h+2)*64 + j], p2);
        p3 = fmaf(dsumC[h0+h+3], Wd1T[(h0+h+3)*64 + j], p3);
      }
      dsumP[tid] = (p0+p1) + (p2+p3);            // gz partials (t in ebw)
    } else {
      const int o = tid - 128;
      const float a = rsh[o] + zw1[o];
      f2sh[o] = a * sigf(a);                     // own-wave slot (64/wave)
      wave_sync();                               // f2sh half visible in-wave
      const int j = o & 63, h0 = (o >> 6) * 64;  // reads own wave's half
      float p0 = (h0 == 0) ? bf3sh[j] : 0.f;
      float p1 = 0.f, p2 = 0.f, p3 = 0.f;
      #pragma unroll 4
      for (int h = 0; h < 64; h += 4) {
        p0 = fmaf(f2sh[h0+h+0], Wf3[(h0+h+0)*ZD + j], p0);
        p1 = fmaf(f2sh[h0+h+1], Wf3[(h0+h+1)*ZD + j], p1);
        p2 = fmaf(f2sh[h0+h+2], Wf3[(h0+h+2)*ZD + j], p2);
        p3 = fmaf(f2sh[h0+h+3], Wf3[(h0+h+3)*ZD + j], p3);
      }
      bgz[o] = (p0+p1) + (p2+p3);                // f3 partials
    }
    __syncthreads();   // B5: partials ready (cross-wave reads next)

    // ---- update: redundant on ALL waves; zold from step-top register.
    {
      const float bdrift = bgz[zi] + bgz[64 + zi];
      const float gzv    = dsumP[zi] + dsumP[64 + zi];
      float g = zold_r + gzv;
      g = fminf(fmaxf(g, -100.0f), 100.0f);
      zsh[zi] = zold_r + (bdrift - g) * dt + dco * noise_v;
    }
    wave_sync();       // own-wave zsh writes drained
  }

  if (tid < 64) out[b * ZD + tid] = zsh[tid];
}

extern "C" void kernel_launch(void* const* d_in, const int* in_sizes, int n_in,
                              void* d_out, int out_size, void* d_ws, size_t ws_size,
                              hipStream_t stream) {
  const float* x_ctx  = (const float*)d_in[0];
  const float* y_ctx  = (const float*)d_in[1];
  const float* mask   = (const float*)d_in[2];
  const float* z0     = (const float*)d_in[3];
  const float* noises = (const float*)d_in[4];
  const float* We1 = (const float*)d_in[5];  const float* be1 = (const float*)d_in[6];
  const float* We2 = (const float*)d_in[7];  const float* be2 = (const float*)d_in[8];
  const float* We3 = (const float*)d_in[9];  const float* be3 = (const float*)d_in[10];
  const float* Wd1 = (const float*)d_in[11]; const float* bd1 = (const float*)d_in[12];
  const float* Wd2 = (const float*)d_in[13]; const float* bd2 = (const float*)d_in[14];
  const float* Wd3 = (const float*)d_in[15]; const float* bd3 = (const float*)d_in[16];
  const float* Wf1 = (const float*)d_in[17]; const float* bf1 = (const float*)d_in[18];
  const float* Wf2 = (const float*)d_in[19]; const float* bf2 = (const float*)d_in[20];
  const float* Wf3 = (const float*)d_in[21]; const float* bf3 = (const float*)d_in[22];

  const int steps = in_sizes[4] / (B_TOT * ZD);
  const float dt  = 1.0f / (float)steps;
  const float dco = (float)sqrt(2.0 / (double)steps);

  ushort* wsu = (ushort*)d_ws;   // 128KB frag arrays + 32KB Wd1T

  hipLaunchKernelGGL(prep_kernel, dim3(288), dim3(256), 0, stream,
                     Wd2, We2, We3, Wd1, wsu);
  hipLaunchKernelGGL(metanets_kernel, dim3(B_TOT), dim3(256), 0, stream,
      x_ctx, y_ctx, mask, z0, noises,
      We1, be1, be2, be3,
      Wd1, bd1, bd2, Wd3, bd3,
      Wf1, bf1, Wf2, bf2, Wf3, bf3,
      wsu, (float*)d_out, steps, dt, dco);
}